// Round 2
// baseline (150.617 us; speedup 1.0000x reference)
//
#include <hip/hip_runtime.h>

// LBP 8-neighbor extractor, 8192x8192 f32 -> codes 0..255 written as int32.
// Reference semantics: dx/dy = -1 wraps (python negative indexing / jnp.roll);
// dx/dy = +1 past the edge contributes 0 (IndexError path in the original).
// Harness reads d_out via the int32 path (reference output dtype is uint8/int).

constexpr int TPB = 256;  // threads per block
constexpr int PX  = 4;    // pixels per thread (float4 in / int4 out)

__global__ __launch_bounds__(TPB) void lbp_kernel(const float* __restrict__ img,
                                                  int* __restrict__ out,
                                                  int H, int W) {
    const int r  = blockIdx.y;
    const int c0 = (blockIdx.x * TPB + threadIdx.x) * PX;
    if (c0 >= W) return;

    // row above: wraps at r==0 (python -1 index)
    const int  rm       = (r == 0) ? (H - 1) : (r - 1);
    // row below: invalid past the bottom edge
    const bool dn_valid = (r + 1) < H;
    const int  rp       = dn_valid ? (r + 1) : 0;

    const size_t baseC = (size_t)r  * W;
    const size_t baseM = (size_t)rm * W;
    const size_t baseP = (size_t)rp * W;

    const float4 c4 = *reinterpret_cast<const float4*>(img + baseC + c0);
    const float4 u4 = *reinterpret_cast<const float4*>(img + baseM + c0);
    const float4 d4 = dn_valid ? *reinterpret_cast<const float4*>(img + baseP + c0)
                               : make_float4(0.f, 0.f, 0.f, 0.f);

    // left halo column: wraps at c0==0 (python -1 index)
    const int  cl = (c0 == 0) ? (W - 1) : (c0 - 1);
    // right halo column: invalid past the right edge (only matters for i == PX-1)
    const bool rv = (c0 + PX) < W;
    const int  cr = rv ? (c0 + PX) : 0;

    float C[6], U[6], D[6];
    C[0] = img[baseC + cl]; C[1] = c4.x; C[2] = c4.y; C[3] = c4.z; C[4] = c4.w; C[5] = img[baseC + cr];
    U[0] = img[baseM + cl]; U[1] = u4.x; U[2] = u4.y; U[3] = u4.z; U[4] = u4.w; U[5] = img[baseM + cr];
    D[0] = 0.f; D[1] = 0.f; D[2] = 0.f; D[3] = 0.f; D[4] = 0.f; D[5] = 0.f;
    if (dn_valid) {
        D[0] = img[baseP + cl]; D[1] = d4.x; D[2] = d4.y; D[3] = d4.z; D[4] = d4.w; D[5] = img[baseP + cr];
    }

    int res[PX];
    #pragma unroll
    for (int i = 0; i < PX; ++i) {
        const float cen  = C[i + 1];
        const bool  colv = (i < PX - 1) || rv;  // right-neighbor (col+1) validity
        int acc = 0;
        // clockwise offsets, bit weights 1..128:
        acc += (U[i]     >= cen) ?   1 : 0;                 // (-1,-1) wraps, always valid
        acc += (U[i + 1] >= cen) ?   2 : 0;                 // (-1, 0) wraps, always valid
        acc += (colv && (U[i + 2] >= cen)) ?  4 : 0;        // (-1,+1)
        acc += (colv && (C[i + 2] >= cen)) ?  8 : 0;        // ( 0,+1)
        if (dn_valid) {
            acc += (colv && (D[i + 2] >= cen)) ? 16 : 0;    // (+1,+1)
            acc += (D[i + 1] >= cen) ? 32 : 0;              // (+1, 0)
            acc += (D[i]     >= cen) ? 64 : 0;              // (+1,-1)
        }
        acc += (C[i] >= cen) ? 128 : 0;                     // ( 0,-1) wraps, always valid
        res[i] = acc;
    }

    *reinterpret_cast<int4*>(out + baseC + c0) = make_int4(res[0], res[1], res[2], res[3]);
}

extern "C" void kernel_launch(void* const* d_in, const int* in_sizes, int n_in,
                              void* d_out, int out_size, void* d_ws, size_t ws_size,
                              hipStream_t stream) {
    const float* img = (const float*)d_in[0];
    int*         out = (int*)d_out;
    const int H = 8192, W = 8192;
    dim3 grid(W / (TPB * PX), H);  // (8, 8192)
    lbp_kernel<<<grid, dim3(TPB), 0, stream>>>(img, out, H, W);
}

// Round 4
// 90.198 us; speedup vs baseline: 1.6698x; 1.6698x over previous
//
#include <hip/hip_runtime.h>

// LBP 8-neighbor extractor, 8192x8192 f32 -> codes 0..255 written as int32.
// Reference semantics: dx/dy = -1 wraps (python negative indexing / jnp.roll);
// dx/dy = +1 past the edge contributes 0 (IndexError path in the original).
//
// R4: halo values via wave shuffles (only lanes 0/63 issue a scalar halo load)
// to cut L1 cache-line accesses/wave from ~160 to ~68; non-temporal output
// store (via clang ext_vector_type — HIP int4 is a class and rejected by the
// builtin) so the 256 MB input stays L3-resident.

constexpr int TPB = 256;  // threads per block
constexpr int PX  = 4;    // pixels per thread (float4 in / int4 out)

typedef int v4i __attribute__((ext_vector_type(4)));

__global__ __launch_bounds__(TPB) void lbp_kernel(const float* __restrict__ img,
                                                  int* __restrict__ out,
                                                  int H, int W) {
    const int r    = blockIdx.y;
    const int c0   = (blockIdx.x * TPB + threadIdx.x) * PX;
    const int lane = threadIdx.x & 63;

    // row above: wraps at r==0 (python -1 index)
    const int  rm       = (r == 0) ? (H - 1) : (r - 1);
    // row below: invalid past the bottom edge
    const bool dn_valid = (r + 1) < H;
    const int  rp       = dn_valid ? (r + 1) : 0;

    const size_t baseC = (size_t)r  * W;
    const size_t baseM = (size_t)rm * W;
    const size_t baseP = (size_t)rp * W;

    const float4 c4 = *reinterpret_cast<const float4*>(img + baseC + c0);
    const float4 u4 = *reinterpret_cast<const float4*>(img + baseM + c0);
    float4 d4 = make_float4(0.f, 0.f, 0.f, 0.f);
    if (dn_valid) {  // wave-uniform branch (r is uniform per block)
        d4 = *reinterpret_cast<const float4*>(img + baseP + c0);
    }

    // Halo columns via in-wave shuffle: left = lane-1's .w, right = lane+1's .x.
    float lC = __shfl_up(c4.w, 1);
    float lU = __shfl_up(u4.w, 1);
    float lD = __shfl_up(d4.w, 1);
    float rC = __shfl_down(c4.x, 1);
    float rU = __shfl_down(u4.x, 1);
    float rD = __shfl_down(d4.x, 1);

    if (lane == 0) {  // cross-wave (or wrapped) left halo: 1-lane scalar loads
        const int cl = (c0 == 0) ? (W - 1) : (c0 - 1);
        lC = img[baseC + cl];
        lU = img[baseM + cl];
        lD = dn_valid ? img[baseP + cl] : 0.f;
    }
    const bool rv = (c0 + PX) < W;  // right-edge validity (col W is IndexError -> 0)
    if (lane == 63) {  // cross-wave right halo
        const int cr = rv ? (c0 + PX) : 0;
        rC = rv ? img[baseC + cr] : 0.f;
        rU = rv ? img[baseM + cr] : 0.f;
        rD = (rv && dn_valid) ? img[baseP + cr] : 0.f;
    }

    const float C[6] = {lC, c4.x, c4.y, c4.z, c4.w, rC};
    const float U[6] = {lU, u4.x, u4.y, u4.z, u4.w, rU};
    const float D[6] = {lD, d4.x, d4.y, d4.z, d4.w, rD};

    int res[PX];
    #pragma unroll
    for (int i = 0; i < PX; ++i) {
        const float cen  = C[i + 1];
        const bool  colv = (i < PX - 1) || rv;  // right-neighbor (col+1) validity
        int acc = 0;
        // clockwise offsets, bit weights 1..128:
        acc += (U[i]     >= cen) ?   1 : 0;                 // (-1,-1) wraps, always valid
        acc += (U[i + 1] >= cen) ?   2 : 0;                 // (-1, 0) wraps, always valid
        acc += (colv && (U[i + 2] >= cen)) ?  4 : 0;        // (-1,+1)
        acc += (colv && (C[i + 2] >= cen)) ?  8 : 0;        // ( 0,+1)
        if (dn_valid) {
            acc += (colv && (D[i + 2] >= cen)) ? 16 : 0;    // (+1,+1)
            acc += (D[i + 1] >= cen) ? 32 : 0;              // (+1, 0)
            acc += (D[i]     >= cen) ? 64 : 0;              // (+1,-1)
        }
        acc += (C[i] >= cen) ? 128 : 0;                     // ( 0,-1) wraps, always valid
        res[i] = acc;
    }

    v4i v;
    v.x = res[0]; v.y = res[1]; v.z = res[2]; v.w = res[3];
    __builtin_nontemporal_store(v, reinterpret_cast<v4i*>(out + baseC + c0));
}

extern "C" void kernel_launch(void* const* d_in, const int* in_sizes, int n_in,
                              void* d_out, int out_size, void* d_ws, size_t ws_size,
                              hipStream_t stream) {
    const float* img = (const float*)d_in[0];
    int*         out = (int*)d_out;
    const int H = 8192, W = 8192;
    dim3 grid(W / (TPB * PX), H);  // (8, 8192)
    lbp_kernel<<<grid, dim3(TPB), 0, stream>>>(img, out, H, W);
}

// Round 5
// 81.850 us; speedup vs baseline: 1.8402x; 1.1020x over previous
//
#include <hip/hip_runtime.h>

// LBP 8-neighbor extractor, 8192x8192 f32 -> codes 0..255 written as int32.
// Reference semantics: dx/dy = -1 wraps (python negative indexing / jnp.roll);
// dx/dy = +1 past the edge contributes 0 (IndexError path in the original).
//
// R5: 2 output rows per thread (load 4 rows, emit 2) -> row-loads per output
// 3 -> 2; halo columns via wave shuffles (lanes 0/63 scalar-fix); NT int4
// stores keep the output out of L3 so the input stays resident.

constexpr int TPB = 256;  // threads per block
constexpr int PX  = 4;    // pixels per thread per row (float4 in / int4 out)

typedef int v4i __attribute__((ext_vector_type(4)));

__device__ __forceinline__ void lbp_row(const float* U, const float* C, const float* D,
                                        bool dnv, bool rv, int* res) {
    #pragma unroll
    for (int i = 0; i < PX; ++i) {
        const float cen  = C[i + 1];
        const bool  colv = (i < PX - 1) || rv;  // right-neighbor (col+1) validity
        int acc = 0;
        // clockwise offsets, bit weights 1..128:
        acc += (U[i]     >= cen) ?   1 : 0;                 // (-1,-1) wraps, always valid
        acc += (U[i + 1] >= cen) ?   2 : 0;                 // (-1, 0) wraps, always valid
        acc += (colv && (U[i + 2] >= cen)) ?  4 : 0;        // (-1,+1)
        acc += (colv && (C[i + 2] >= cen)) ?  8 : 0;        // ( 0,+1)
        if (dnv) {
            acc += (colv && (D[i + 2] >= cen)) ? 16 : 0;    // (+1,+1)
            acc += (D[i + 1] >= cen) ? 32 : 0;              // (+1, 0)
            acc += (D[i]     >= cen) ? 64 : 0;              // (+1,-1)
        }
        acc += (C[i] >= cen) ? 128 : 0;                     // ( 0,-1) wraps, always valid
        res[i] = acc;
    }
}

__global__ __launch_bounds__(TPB) void lbp_kernel(const float* __restrict__ img,
                                                  int* __restrict__ out,
                                                  int H, int W) {
    const int r0   = blockIdx.y * 2;                    // emit rows r0, r0+1
    const int c0   = (blockIdx.x * TPB + threadIdx.x) * PX;
    const int lane = threadIdx.x & 63;

    // 4 source rows: A = r0-1 (wraps at r0==0), B = r0, C = r0+1 (always < H),
    // D = r0+2 (invalid at r0 == H-2 -> contributes 0).
    const int  rA      = (r0 == 0) ? (H - 1) : (r0 - 1);
    const bool d_valid = (r0 + 2) < H;
    const int  rD      = d_valid ? (r0 + 2) : 0;

    const size_t base[4] = {(size_t)rA * W, (size_t)r0 * W,
                            (size_t)(r0 + 1) * W, (size_t)rD * W};

    float4 v4[4];
    v4[0] = *reinterpret_cast<const float4*>(img + base[0] + c0);
    v4[1] = *reinterpret_cast<const float4*>(img + base[1] + c0);
    v4[2] = *reinterpret_cast<const float4*>(img + base[2] + c0);
    v4[3] = d_valid ? *reinterpret_cast<const float4*>(img + base[3] + c0)
                    : make_float4(0.f, 0.f, 0.f, 0.f);

    const bool rv = (c0 + PX) < W;  // right-edge validity (col W is IndexError -> 0)

    float R[4][6];
    #pragma unroll
    for (int k = 0; k < 4; ++k) {
        float lh = __shfl_up(v4[k].w, 1);    // left halo from lane-1
        float rh = __shfl_down(v4[k].x, 1);  // right halo from lane+1
        R[k][0] = lh; R[k][1] = v4[k].x; R[k][2] = v4[k].y;
        R[k][3] = v4[k].z; R[k][4] = v4[k].w; R[k][5] = rh;
    }
    if (lane == 0) {  // cross-wave (or wrapped) left halo: 1-lane scalar loads
        const int cl = (c0 == 0) ? (W - 1) : (c0 - 1);
        R[0][0] = img[base[0] + cl];
        R[1][0] = img[base[1] + cl];
        R[2][0] = img[base[2] + cl];
        R[3][0] = d_valid ? img[base[3] + cl] : 0.f;
    }
    if (lane == 63) {  // cross-wave right halo
        const int cr = rv ? (c0 + PX) : 0;
        R[0][5] = rv ? img[base[0] + cr] : 0.f;
        R[1][5] = rv ? img[base[1] + cr] : 0.f;
        R[2][5] = rv ? img[base[2] + cr] : 0.f;
        R[3][5] = (rv && d_valid) ? img[base[3] + cr] : 0.f;
    }

    int res0[PX], res1[PX];
    lbp_row(R[0], R[1], R[2], true,    rv, res0);  // row r0: down-row r0+1 always valid
    lbp_row(R[1], R[2], R[3], d_valid, rv, res1);  // row r0+1: down-row r0+2

    v4i s0; s0.x = res0[0]; s0.y = res0[1]; s0.z = res0[2]; s0.w = res0[3];
    v4i s1; s1.x = res1[0]; s1.y = res1[1]; s1.z = res1[2]; s1.w = res1[3];
    __builtin_nontemporal_store(s0, reinterpret_cast<v4i*>(out + base[1] + c0));
    __builtin_nontemporal_store(s1, reinterpret_cast<v4i*>(out + base[2] + c0));
}

extern "C" void kernel_launch(void* const* d_in, const int* in_sizes, int n_in,
                              void* d_out, int out_size, void* d_ws, size_t ws_size,
                              hipStream_t stream) {
    const float* img = (const float*)d_in[0];
    int*         out = (int*)d_out;
    const int H = 8192, W = 8192;
    dim3 grid(W / (TPB * PX), H / 2);  // (8, 4096)
    lbp_kernel<<<grid, dim3(TPB), 0, stream>>>(img, out, H, W);
}